// Round 6
// baseline (208.940 us; speedup 1.0000x reference)
//
#include <hip/hip_runtime.h>
#include <math.h>

#define MARGIN  23.0f
#define MARGIN2 529.0f   // 23^2, exact in f32
#define DIM 256
#define NUM_POS 100000
#define NUM_NEG 100000

#define BLOCK 256
#define WAVES_PER_BLOCK (BLOCK / 64)
#define NBLOCKS 1250                 // 5 blocks/CU x 250 CUs used; <= 1280 co-resident
#define NW (NBLOCKS * WAVES_PER_BLOCK)  // 5000 waves
#define SG_ROWS 8                    // rows per supergroup (8 KiB)
#define SG_POS (NUM_POS / SG_ROWS)   // 12500 pos supergroups
#define SG_PER_WAVE 5                // 5000 waves x 5 sg x 8 rows = 200000 EXACT

typedef float v4f __attribute__((ext_vector_type(4)));

// Stage 1, R6: 16 lanes per row; each wave-iteration processes one SUPERGROUP
// of 8 consecutive rows (8 KiB): lane (q,t) covers row sg*8+q and row sg*8+4+q.
// 8 nt loads in flight per wave (2x R5's MLP), one vmcnt drain per 8 KiB
// (half R5's sync cadence), two independent 4-step shuffle chains interleaved.
// Uniform trip count (5 supergroups/wave, exact partition, no bounds checks),
// fully unrolled depth-1 pipeline. Non-temporal loads: one-touch stream,
// bypass the L3 half-hit fill path (R4's win).
//
// ws layout (floats, all SQUARED distances):
//   ws[0]                       = d_pos[0]^2 fallback
//   ws[1 .. NBLOCKS]            = per-block pos max (masked)
//   ws[1+NBLOCKS .. 2*NBLOCKS]  = per-block neg min
__global__ __launch_bounds__(BLOCK, 5) void triplet_stage1(
    const float* __restrict__ anchor,
    const float* __restrict__ pos,
    const float* __restrict__ neg,
    float* __restrict__ ws) {
  __shared__ float s_pos[WAVES_PER_BLOCK];
  __shared__ float s_neg[WAVES_PER_BLOCK];

  const int lane = threadIdx.x & 63;
  const int wid  = threadIdx.x >> 6;
  const int t    = lane & 15;   // segment within row
  const int q    = lane >> 4;   // row-pair selector within supergroup

  // Anchor fragments (reused; cached loads). Same t-mapping for both halves.
  const v4f* af = reinterpret_cast<const v4f*>(anchor);
  const v4f a0 = af[t];
  const v4f a1 = af[t + 16];
  const v4f a2 = af[t + 32];
  const v4f a3 = af[t + 48];

  const int w = blockIdx.x * WAVES_PER_BLOCK + wid;
  const int lo = q * (DIM / 4) + t;        // v4f index of row q, seg t
  const int hi = (q + 4) * (DIM / 4) + t;  // v4f index of row q+4, seg t

  auto load_sg = [&](v4f* B, int g) {
    const float* base = (g < SG_POS)
                            ? pos + (size_t)g * (SG_ROWS * DIM)
                            : neg + (size_t)(g - SG_POS) * (SG_ROWS * DIM);
    const v4f* rp = reinterpret_cast<const v4f*>(base);
    B[0] = __builtin_nontemporal_load(rp + lo);
    B[1] = __builtin_nontemporal_load(rp + lo + 16);
    B[2] = __builtin_nontemporal_load(rp + lo + 32);
    B[3] = __builtin_nontemporal_load(rp + lo + 48);
    B[4] = __builtin_nontemporal_load(rp + hi);
    B[5] = __builtin_nontemporal_load(rp + hi + 16);
    B[6] = __builtin_nontemporal_load(rp + hi + 32);
    B[7] = __builtin_nontemporal_load(rp + hi + 48);
  };

  float pmax = -INFINITY;  // squared space
  float nmin =  INFINITY;

  v4f P[8];
  load_sg(P, w * SG_PER_WAVE);

  #pragma unroll
  for (int i = 0; i < SG_PER_WAVE; ++i) {
    const int g = w * SG_PER_WAVE + i;
    v4f N[8];
    if (i + 1 < SG_PER_WAVE) load_sg(N, g + 1);  // depth-1 prefetch

    v4f e;
    float slo, shi;
    e = a0 - P[0]; slo  = e.x * e.x + e.y * e.y + e.z * e.z + e.w * e.w;
    e = a1 - P[1]; slo += e.x * e.x + e.y * e.y + e.z * e.z + e.w * e.w;
    e = a2 - P[2]; slo += e.x * e.x + e.y * e.y + e.z * e.z + e.w * e.w;
    e = a3 - P[3]; slo += e.x * e.x + e.y * e.y + e.z * e.z + e.w * e.w;
    e = a0 - P[4]; shi  = e.x * e.x + e.y * e.y + e.z * e.z + e.w * e.w;
    e = a1 - P[5]; shi += e.x * e.x + e.y * e.y + e.z * e.z + e.w * e.w;
    e = a2 - P[6]; shi += e.x * e.x + e.y * e.y + e.z * e.z + e.w * e.w;
    e = a3 - P[7]; shi += e.x * e.x + e.y * e.y + e.z * e.z + e.w * e.w;

    // Two independent 4-step butterflies over the t bits, interleaved.
    slo += __shfl_xor(slo, 1, 64);  shi += __shfl_xor(shi, 1, 64);
    slo += __shfl_xor(slo, 2, 64);  shi += __shfl_xor(shi, 2, 64);
    slo += __shfl_xor(slo, 4, 64);  shi += __shfl_xor(shi, 4, 64);
    slo += __shfl_xor(slo, 8, 64);  shi += __shfl_xor(shi, 8, 64);
    // slo = ||a - row(8g+q)||^2 ; shi = ||a - row(8g+4+q)||^2

    if (g == 0 && lane == 0) ws[0] = slo;  // row 0 fallback (squared)
    if (g < SG_POS) {
      if (slo < MARGIN2) pmax = fmaxf(pmax, slo);
      if (shi < MARGIN2) pmax = fmaxf(pmax, shi);
    } else {
      nmin = fminf(nmin, slo);
      nmin = fminf(nmin, shi);
    }

    #pragma unroll
    for (int k = 0; k < 8; ++k) P[k] = N[k];
  }

  // Cross-quarter combine (lanes within a 16-lane group hold identical values).
  pmax = fmaxf(pmax, __shfl_xor(pmax, 16, 64));
  pmax = fmaxf(pmax, __shfl_xor(pmax, 32, 64));
  nmin = fminf(nmin, __shfl_xor(nmin, 16, 64));
  nmin = fminf(nmin, __shfl_xor(nmin, 32, 64));

  if (lane == 0) {
    s_pos[wid] = pmax;
    s_neg[wid] = nmin;
  }
  __syncthreads();

  if (threadIdx.x == 0) {
    float pm = s_pos[0];
    float nm = s_neg[0];
    #pragma unroll
    for (int i = 1; i < WAVES_PER_BLOCK; ++i) {
      pm = fmaxf(pm, s_pos[i]);
      nm = fminf(nm, s_neg[i]);
    }
    ws[1 + blockIdx.x] = pm;
    ws[1 + NBLOCKS + blockIdx.x] = nm;
  }
}

// Stage 2: reduce NBLOCKS partials (squared space), sqrt once, write loss.
__global__ __launch_bounds__(BLOCK) void triplet_stage2(
    const float* __restrict__ ws,
    float* __restrict__ out) {
  __shared__ float s_pos[WAVES_PER_BLOCK];
  __shared__ float s_neg[WAVES_PER_BLOCK];

  const int lane = threadIdx.x & 63;
  const int wid  = threadIdx.x >> 6;

  float pm = -INFINITY;
  float nm =  INFINITY;
  for (int i = threadIdx.x; i < NBLOCKS; i += BLOCK) {
    pm = fmaxf(pm, ws[1 + i]);
    nm = fminf(nm, ws[1 + NBLOCKS + i]);
  }
  #pragma unroll
  for (int off = 32; off > 0; off >>= 1) {
    pm = fmaxf(pm, __shfl_xor(pm, off, 64));
    nm = fminf(nm, __shfl_xor(nm, off, 64));
  }
  if (lane == 0) {
    s_pos[wid] = pm;
    s_neg[wid] = nm;
  }
  __syncthreads();
  if (threadIdx.x == 0) {
    float fpm = s_pos[0];
    float fnm = s_neg[0];
    #pragma unroll
    for (int i = 1; i < WAVES_PER_BLOCK; ++i) {
      fpm = fmaxf(fpm, s_pos[i]);
      fnm = fminf(fnm, s_neg[i]);
    }
    if (fpm == -INFINITY) fpm = ws[0];  // no positive under margin -> index 0
    out[0] = fmaxf(sqrtf(fpm) - sqrtf(fnm) + MARGIN, 0.0f);
  }
}

extern "C" void kernel_launch(void* const* d_in, const int* in_sizes, int n_in,
                              void* d_out, int out_size, void* d_ws, size_t ws_size,
                              hipStream_t stream) {
  const float* anchor = (const float*)d_in[0];
  const float* pos    = (const float*)d_in[1];
  const float* neg    = (const float*)d_in[2];
  float* out = (float*)d_out;
  float* ws  = (float*)d_ws;

  triplet_stage1<<<NBLOCKS, BLOCK, 0, stream>>>(anchor, pos, neg, ws);
  triplet_stage2<<<1, BLOCK, 0, stream>>>(ws, out);
}